// Round 1
// baseline (210.196 us; speedup 1.0000x reference)
//
#include <hip/hip_runtime.h>
#include <math.h>

#define NS   512
#define NOBJ 16
#define MPTS 8192
#define HH   128
#define WW   128
#define HW   (HH * WW)
#define BLOCK 256

// Projection through full 3x3 K (third row is [0,0,1] in practice, but keep general).
__device__ __forceinline__ void project(const float K[9], float x, float y, float z,
                                        float& u, float& v) {
    float w  = K[6] * x + K[7] * y + K[8] * z;
    float iw = 1.0f / w;
    u = (K[0] * x + K[1] * y + K[2] * z) * iw;
    v = (K[3] * x + K[4] * y + K[5] * z) * iw;
}

__global__ __launch_bounds__(BLOCK) void score_kernel(
    const int*   __restrict__ obj_id,     // [N]
    const float* __restrict__ cam_K,      // [N,3,3]
    const float* __restrict__ gt_R,       // [N,3,3]
    const float* __restrict__ gt_t,       // [N,3]
    const float* __restrict__ pr_R,       // [N,3,3]
    const float* __restrict__ pr_t,       // [N,3]
    const float* __restrict__ coord,      // [N,3,H,W]
    const int*   __restrict__ mask,       // [N,1,H,W]  (bool normalized; !=0 test)
    const float* __restrict__ mesh,       // [NOBJ,M,3]
    const float* __restrict__ diam,       // [NOBJ]
    float*       __restrict__ out)        // [5*N] : re | te | ad | pj | pv
{
    const int n   = blockIdx.x;
    const int tid = threadIdx.x;

    // ---- per-sample uniforms (blockIdx-uniform -> scalar loads) ----
    float K[9], Rg[9], Rp[9];
    float tg[3], tp[3];
#pragma unroll
    for (int i = 0; i < 9; ++i) {
        K[i]  = cam_K[n * 9 + i];
        Rg[i] = gt_R [n * 9 + i];
        Rp[i] = pr_R [n * 9 + i];
    }
#pragma unroll
    for (int i = 0; i < 3; ++i) {
        tg[i] = gt_t[n * 3 + i];
        tp[i] = pr_t[n * 3 + i];
    }
    const int   obj = obj_id[n];
    const float dia = diam[obj];

    float dR[9], dt[3];
#pragma unroll
    for (int i = 0; i < 9; ++i) dR[i] = Rp[i] - Rg[i];
#pragma unroll
    for (int i = 0; i < 3; ++i) dt[i] = tp[i] - tg[i];

    // ---- phase 1: mesh loop (ad + pj) ----
    float s_ad = 0.0f, s_pj = 0.0f;
    const float* mp = mesh + (size_t)obj * MPTS * 3;
    for (int m = tid; m < MPTS; m += BLOCK) {
        const float px = mp[m * 3 + 0];
        const float py = mp[m * 3 + 1];
        const float pz = mp[m * 3 + 2];
        // ad
        const float dx = dR[0] * px + dR[1] * py + dR[2] * pz + dt[0];
        const float dy = dR[3] * px + dR[4] * py + dR[5] * pz + dt[1];
        const float dz = dR[6] * px + dR[7] * py + dR[8] * pz + dt[2];
        s_ad += sqrtf(dx * dx + dy * dy + dz * dz);
        // pj
        const float apx = Rp[0] * px + Rp[1] * py + Rp[2] * pz + tp[0];
        const float apy = Rp[3] * px + Rp[4] * py + Rp[5] * pz + tp[1];
        const float apz = Rp[6] * px + Rp[7] * py + Rp[8] * pz + tp[2];
        const float agx = Rg[0] * px + Rg[1] * py + Rg[2] * pz + tg[0];
        const float agy = Rg[3] * px + Rg[4] * py + Rg[5] * pz + tg[1];
        const float agz = Rg[6] * px + Rg[7] * py + Rg[8] * pz + tg[2];
        float up, vp, ug, vg;
        project(K, apx, apy, apz, up, vp);
        project(K, agx, agy, agz, ug, vg);
        const float du = up - ug, dv = vp - vg;
        s_pj += sqrtf(du * du + dv * dv);
    }

    // ---- phase 2: ROI pixel loop (pv), float4/int4 vectorized ----
    const float* cx = coord + (size_t)n * 3 * HW;
    const float* cy = cx + HW;
    const float* cz = cy + HW;
    const int*   mk = mask + (size_t)n * HW;

    float s_pv = 0.0f, s_m = 0.0f;
    const float4* cx4 = (const float4*)cx;
    const float4* cy4 = (const float4*)cy;
    const float4* cz4 = (const float4*)cz;
    const int4*   mk4 = (const int4*)mk;

    for (int p = tid; p < HW / 4; p += BLOCK) {
        const float4 vx = cx4[p];
        const float4 vy = cy4[p];
        const float4 vz = cz4[p];
        const int4   mm = mk4[p];

        const float xs[4] = {vx.x, vx.y, vx.z, vx.w};
        const float ys[4] = {vy.x, vy.y, vy.z, vy.w};
        const float zs[4] = {vz.x, vz.y, vz.z, vz.w};
        const int   ms[4] = {mm.x, mm.y, mm.z, mm.w};

#pragma unroll
        for (int j = 0; j < 4; ++j) {
            const float x = xs[j], y = ys[j], z = zs[j];
            const float apx = Rp[0] * x + Rp[1] * y + Rp[2] * z + tp[0];
            const float apy = Rp[3] * x + Rp[4] * y + Rp[5] * z + tp[1];
            const float apz = Rp[6] * x + Rp[7] * y + Rp[8] * z + tp[2];
            const float agx = Rg[0] * x + Rg[1] * y + Rg[2] * z + tg[0];
            const float agy = Rg[3] * x + Rg[4] * y + Rg[5] * z + tg[1];
            const float agz = Rg[6] * x + Rg[7] * y + Rg[8] * z + tg[2];
            float up, vp, ug, vg;
            project(K, apx, apy, apz, up, vp);
            project(K, agx, agy, agz, ug, vg);
            const float du = up - ug, dv = vp - vg;
            const float d  = sqrtf(du * du + dv * dv);
            const float fm = (ms[j] != 0) ? 1.0f : 0.0f;
            s_pv += d * fm;   // mirrors ref's (d * mask).sum semantics
            s_m  += fm;
        }
    }

    // ---- block reduction: 4 sums, wave64 shuffle then LDS ----
    float vals[4] = {s_ad, s_pj, s_pv, s_m};
#pragma unroll
    for (int k = 0; k < 4; ++k) {
#pragma unroll
        for (int off = 32; off > 0; off >>= 1)
            vals[k] += __shfl_down(vals[k], off, 64);
    }

    __shared__ float red[4][BLOCK / 64];
    const int wave = tid >> 6;
    const int lane = tid & 63;
    if (lane == 0) {
#pragma unroll
        for (int k = 0; k < 4; ++k) red[k][wave] = vals[k];
    }
    __syncthreads();

    if (tid == 0) {
        float tot[4];
#pragma unroll
        for (int k = 0; k < 4; ++k) {
            float s = 0.0f;
#pragma unroll
            for (int w = 0; w < BLOCK / 64; ++w) s += red[k][w];
            tot[k] = s;
        }

        // re (degrees): trace(Rp @ Rg^T) = sum_ij Rp[ij]*Rg[ij]
        float trace = 0.0f;
#pragma unroll
        for (int i = 0; i < 9; ++i) trace += Rp[i] * Rg[i];
        trace = fminf(fmaxf(trace, -1.0f), 3.0f);
        const float re = acosf((trace - 1.0f) * 0.5f) * (180.0f / 3.14159265358979323846f);

        // te (cm)
        const float te = sqrtf(dt[0] * dt[0] + dt[1] * dt[1] + dt[2] * dt[2]) * 100.0f;

        out[0 * NS + n] = re;
        out[1 * NS + n] = te;
        out[2 * NS + n] = tot[0] * (1.0f / MPTS) / dia;
        out[3 * NS + n] = tot[1] * (1.0f / MPTS);
        out[4 * NS + n] = tot[2] / fmaxf(tot[3], 1.0f);
    }
}

extern "C" void kernel_launch(void* const* d_in, const int* in_sizes, int n_in,
                              void* d_out, int out_size, void* d_ws, size_t ws_size,
                              hipStream_t stream) {
    const int*   obj_id = (const int*)  d_in[0];
    const float* cam_K  = (const float*)d_in[1];
    const float* gt_R   = (const float*)d_in[2];
    const float* gt_t   = (const float*)d_in[3];
    const float* pr_R   = (const float*)d_in[4];
    const float* pr_t   = (const float*)d_in[5];
    const float* coord  = (const float*)d_in[6];
    const int*   mask   = (const int*)  d_in[7];
    const float* mesh   = (const float*)d_in[8];
    const float* diam   = (const float*)d_in[9];
    float* out = (float*)d_out;

    score_kernel<<<NS, BLOCK, 0, stream>>>(obj_id, cam_K, gt_R, gt_t, pr_R, pr_t,
                                           coord, mask, mesh, diam, out);
}

// Round 2
// 192.365 us; speedup vs baseline: 1.0927x; 1.0927x over previous
//
#include <hip/hip_runtime.h>
#include <math.h>

#define NS   512
#define NOBJ 16
#define MPTS 8192
#define HH   128
#define WW   128
#define HW   (HH * WW)
#define BLOCK 1024
#define NWAVE (BLOCK / 64)

// Projection through full 3x3 K (third row is [0,0,1] in practice, but keep general).
__device__ __forceinline__ void project(const float K[9], float x, float y, float z,
                                        float& u, float& v) {
    float w  = K[6] * x + K[7] * y + K[8] * z;
    float iw = 1.0f / w;
    u = (K[0] * x + K[1] * y + K[2] * z) * iw;
    v = (K[3] * x + K[4] * y + K[5] * z) * iw;
}

__global__ __launch_bounds__(BLOCK) void score_kernel(
    const int*   __restrict__ obj_id,     // [N]
    const float* __restrict__ cam_K,      // [N,3,3]
    const float* __restrict__ gt_R,       // [N,3,3]
    const float* __restrict__ gt_t,       // [N,3]
    const float* __restrict__ pr_R,       // [N,3,3]
    const float* __restrict__ pr_t,       // [N,3]
    const float* __restrict__ coord,      // [N,3,H,W]
    const int*   __restrict__ mask,       // [N,1,H,W]  (bool normalized; !=0 test)
    const float* __restrict__ mesh,       // [NOBJ,M,3]
    const float* __restrict__ diam,       // [NOBJ]
    float*       __restrict__ out)        // [5*N] : re | te | ad | pj | pv
{
    const int n   = blockIdx.x;
    const int tid = threadIdx.x;

    // ---- per-sample uniforms (blockIdx-uniform -> scalar loads) ----
    float K[9], Rg[9], Rp[9];
    float tg[3], tp[3];
#pragma unroll
    for (int i = 0; i < 9; ++i) {
        K[i]  = cam_K[n * 9 + i];
        Rg[i] = gt_R [n * 9 + i];
        Rp[i] = pr_R [n * 9 + i];
    }
#pragma unroll
    for (int i = 0; i < 3; ++i) {
        tg[i] = gt_t[n * 3 + i];
        tp[i] = pr_t[n * 3 + i];
    }
    const int   obj = obj_id[n];
    const float dia = diam[obj];

    float dR[9], dt[3];
#pragma unroll
    for (int i = 0; i < 9; ++i) dR[i] = Rp[i] - Rg[i];
#pragma unroll
    for (int i = 0; i < 3; ++i) dt[i] = tp[i] - tg[i];

    // ---- phase 1: mesh loop (ad + pj) ----
    float s_ad = 0.0f, s_pj = 0.0f;
    const float* mp = mesh + (size_t)obj * MPTS * 3;
#pragma unroll
    for (int it = 0; it < MPTS / BLOCK; ++it) {
        const int m = it * BLOCK + tid;
        const float px = mp[m * 3 + 0];
        const float py = mp[m * 3 + 1];
        const float pz = mp[m * 3 + 2];
        // ad
        const float dx = dR[0] * px + dR[1] * py + dR[2] * pz + dt[0];
        const float dy = dR[3] * px + dR[4] * py + dR[5] * pz + dt[1];
        const float dz = dR[6] * px + dR[7] * py + dR[8] * pz + dt[2];
        s_ad += sqrtf(dx * dx + dy * dy + dz * dz);
        // pj
        const float apx = Rp[0] * px + Rp[1] * py + Rp[2] * pz + tp[0];
        const float apy = Rp[3] * px + Rp[4] * py + Rp[5] * pz + tp[1];
        const float apz = Rp[6] * px + Rp[7] * py + Rp[8] * pz + tp[2];
        const float agx = Rg[0] * px + Rg[1] * py + Rg[2] * pz + tg[0];
        const float agy = Rg[3] * px + Rg[4] * py + Rg[5] * pz + tg[1];
        const float agz = Rg[6] * px + Rg[7] * py + Rg[8] * pz + tg[2];
        float up, vp, ug, vg;
        project(K, apx, apy, apz, up, vp);
        project(K, agx, agy, agz, ug, vg);
        const float du = up - ug, dv = vp - vg;
        s_pj += sqrtf(du * du + dv * dv);
    }

    // ---- phase 2: ROI pixel loop (pv), float4/int4 vectorized ----
    const float* cx = coord + (size_t)n * 3 * HW;
    const float* cy = cx + HW;
    const float* cz = cy + HW;
    const int*   mk = mask + (size_t)n * HW;

    float s_pv = 0.0f, s_m = 0.0f;
    const float4* cx4 = (const float4*)cx;
    const float4* cy4 = (const float4*)cy;
    const float4* cz4 = (const float4*)cz;
    const int4*   mk4 = (const int4*)mk;

#pragma unroll
    for (int it = 0; it < HW / 4 / BLOCK; ++it) {
        const int p = it * BLOCK + tid;
        const float4 vx = cx4[p];
        const float4 vy = cy4[p];
        const float4 vz = cz4[p];
        const int4   mm = mk4[p];

        const float xs[4] = {vx.x, vx.y, vx.z, vx.w};
        const float ys[4] = {vy.x, vy.y, vy.z, vy.w};
        const float zs[4] = {vz.x, vz.y, vz.z, vz.w};
        const int   ms[4] = {mm.x, mm.y, mm.z, mm.w};

#pragma unroll
        for (int j = 0; j < 4; ++j) {
            const float x = xs[j], y = ys[j], z = zs[j];
            const float apx = Rp[0] * x + Rp[1] * y + Rp[2] * z + tp[0];
            const float apy = Rp[3] * x + Rp[4] * y + Rp[5] * z + tp[1];
            const float apz = Rp[6] * x + Rp[7] * y + Rp[8] * z + tp[2];
            const float agx = Rg[0] * x + Rg[1] * y + Rg[2] * z + tg[0];
            const float agy = Rg[3] * x + Rg[4] * y + Rg[5] * z + tg[1];
            const float agz = Rg[6] * x + Rg[7] * y + Rg[8] * z + tg[2];
            float up, vp, ug, vg;
            project(K, apx, apy, apz, up, vp);
            project(K, agx, agy, agz, ug, vg);
            const float du = up - ug, dv = vp - vg;
            const float d  = sqrtf(du * du + dv * dv);
            const float fm = (ms[j] != 0) ? 1.0f : 0.0f;
            s_pv += d * fm;   // mirrors ref's (d * mask).sum semantics
            s_m  += fm;
        }
    }

    // ---- block reduction: 4 sums, wave64 shuffle then LDS ----
    float vals[4] = {s_ad, s_pj, s_pv, s_m};
#pragma unroll
    for (int k = 0; k < 4; ++k) {
#pragma unroll
        for (int off = 32; off > 0; off >>= 1)
            vals[k] += __shfl_down(vals[k], off, 64);
    }

    __shared__ float red[4][NWAVE];
    const int wave = tid >> 6;
    const int lane = tid & 63;
    if (lane == 0) {
#pragma unroll
        for (int k = 0; k < 4; ++k) red[k][wave] = vals[k];
    }
    __syncthreads();

    if (tid == 0) {
        float tot[4];
#pragma unroll
        for (int k = 0; k < 4; ++k) {
            float s = 0.0f;
#pragma unroll
            for (int w = 0; w < NWAVE; ++w) s += red[k][w];
            tot[k] = s;
        }

        // re (degrees): trace(Rp @ Rg^T) = sum_ij Rp[ij]*Rg[ij]
        float trace = 0.0f;
#pragma unroll
        for (int i = 0; i < 9; ++i) trace += Rp[i] * Rg[i];
        trace = fminf(fmaxf(trace, -1.0f), 3.0f);
        const float re = acosf((trace - 1.0f) * 0.5f) * (180.0f / 3.14159265358979323846f);

        // te (cm)
        const float te = sqrtf(dt[0] * dt[0] + dt[1] * dt[1] + dt[2] * dt[2]) * 100.0f;

        out[0 * NS + n] = re;
        out[1 * NS + n] = te;
        out[2 * NS + n] = tot[0] * (1.0f / MPTS) / dia;
        out[3 * NS + n] = tot[1] * (1.0f / MPTS);
        out[4 * NS + n] = tot[2] / fmaxf(tot[3], 1.0f);
    }
}

extern "C" void kernel_launch(void* const* d_in, const int* in_sizes, int n_in,
                              void* d_out, int out_size, void* d_ws, size_t ws_size,
                              hipStream_t stream) {
    const int*   obj_id = (const int*)  d_in[0];
    const float* cam_K  = (const float*)d_in[1];
    const float* gt_R   = (const float*)d_in[2];
    const float* gt_t   = (const float*)d_in[3];
    const float* pr_R   = (const float*)d_in[4];
    const float* pr_t   = (const float*)d_in[5];
    const float* coord  = (const float*)d_in[6];
    const int*   mask   = (const int*)  d_in[7];
    const float* mesh   = (const float*)d_in[8];
    const float* diam   = (const float*)d_in[9];
    float* out = (float*)d_out;

    score_kernel<<<NS, BLOCK, 0, stream>>>(obj_id, cam_K, gt_R, gt_t, pr_R, pr_t,
                                           coord, mask, mesh, diam, out);
}

// Round 3
// 190.490 us; speedup vs baseline: 1.1034x; 1.0098x over previous
//
#include <hip/hip_runtime.h>
#include <math.h>

#define NS   512
#define NOBJ 16
#define MPTS 8192
#define HH   128
#define WW   128
#define HW   (HH * WW)
#define BLOCK 1024
#define NWAVE (BLOCK / 64)

__device__ __forceinline__ float frcp(float x)  { return __builtin_amdgcn_rcpf(x); }
__device__ __forceinline__ float fsqrt(float x) { return __builtin_amdgcn_sqrtf(x); }

__global__ __launch_bounds__(BLOCK) void score_kernel(
    const int*   __restrict__ obj_id,     // [N]
    const float* __restrict__ cam_K,      // [N,3,3]
    const float* __restrict__ gt_R,       // [N,3,3]
    const float* __restrict__ gt_t,       // [N,3]
    const float* __restrict__ pr_R,       // [N,3,3]
    const float* __restrict__ pr_t,       // [N,3]
    const float* __restrict__ coord,      // [N,3,H,W]
    const int*   __restrict__ mask,       // [N,1,H,W]
    const float* __restrict__ mesh,       // [NOBJ,M,3]
    const float* __restrict__ diam,       // [NOBJ]
    float*       __restrict__ out)        // [5*N] : re | te | ad | pj | pv
{
    const int n   = blockIdx.x;
    const int tid = threadIdx.x;

    // ---- per-sample uniforms ----
    float K[9], Rg[9], Rp[9], tg[3], tp[3];
#pragma unroll
    for (int i = 0; i < 9; ++i) {
        K[i]  = cam_K[n * 9 + i];
        Rg[i] = gt_R [n * 9 + i];
        Rp[i] = pr_R [n * 9 + i];
    }
#pragma unroll
    for (int i = 0; i < 3; ++i) {
        tg[i] = gt_t[n * 3 + i];
        tp[i] = pr_t[n * 3 + i];
    }
    const int   obj = obj_id[n];
    const float dia = diam[obj];

    float dR[9], dt[3];
#pragma unroll
    for (int i = 0; i < 9; ++i) dR[i] = Rp[i] - Rg[i];
#pragma unroll
    for (int i = 0; i < 3; ++i) dt[i] = tp[i] - tg[i];

    // Fused projection matrices: h = (K*R)*x + (K*t); u = h.x/h.z, v = h.y/h.z
    float Ap[9], Ag[9], bp[3], bg[3];
#pragma unroll
    for (int r = 0; r < 3; ++r) {
#pragma unroll
        for (int c = 0; c < 3; ++c) {
            Ap[r * 3 + c] = K[r * 3 + 0] * Rp[0 * 3 + c]
                          + K[r * 3 + 1] * Rp[1 * 3 + c]
                          + K[r * 3 + 2] * Rp[2 * 3 + c];
            Ag[r * 3 + c] = K[r * 3 + 0] * Rg[0 * 3 + c]
                          + K[r * 3 + 1] * Rg[1 * 3 + c]
                          + K[r * 3 + 2] * Rg[2 * 3 + c];
        }
        bp[r] = K[r * 3 + 0] * tp[0] + K[r * 3 + 1] * tp[1] + K[r * 3 + 2] * tp[2];
        bg[r] = K[r * 3 + 0] * tg[0] + K[r * 3 + 1] * tg[1] + K[r * 3 + 2] * tg[2];
    }

    float s_ad = 0.0f, s_pj = 0.0f;

    // ---- phase 1: mesh loop (ad + pj), 4 points per thread per iter ----
    const float4* mp4 = (const float4*)(mesh + (size_t)obj * MPTS * 3);
#pragma unroll
    for (int it = 0; it < MPTS / (BLOCK * 4); ++it) {
        const int k = it * BLOCK + tid;            // group of 4 points
        const float4 f0 = mp4[k * 3 + 0];
        const float4 f1 = mp4[k * 3 + 1];
        const float4 f2 = mp4[k * 3 + 2];
        const float px[4] = {f0.x, f0.w, f1.z, f2.y};
        const float py[4] = {f0.y, f1.x, f1.w, f2.z};
        const float pz[4] = {f0.z, f1.y, f2.x, f2.w};
#pragma unroll
        for (int j = 0; j < 4; ++j) {
            const float x = px[j], y = py[j], z = pz[j];
            // ad
            const float dx = fmaf(dR[0], x, fmaf(dR[1], y, fmaf(dR[2], z, dt[0])));
            const float dy = fmaf(dR[3], x, fmaf(dR[4], y, fmaf(dR[5], z, dt[1])));
            const float dz = fmaf(dR[6], x, fmaf(dR[7], y, fmaf(dR[8], z, dt[2])));
            s_ad += fsqrt(fmaf(dx, dx, fmaf(dy, dy, dz * dz)));
            // pj (fused projection)
            const float hpx = fmaf(Ap[0], x, fmaf(Ap[1], y, fmaf(Ap[2], z, bp[0])));
            const float hpy = fmaf(Ap[3], x, fmaf(Ap[4], y, fmaf(Ap[5], z, bp[1])));
            const float hpz = fmaf(Ap[6], x, fmaf(Ap[7], y, fmaf(Ap[8], z, bp[2])));
            const float hgx = fmaf(Ag[0], x, fmaf(Ag[1], y, fmaf(Ag[2], z, bg[0])));
            const float hgy = fmaf(Ag[3], x, fmaf(Ag[4], y, fmaf(Ag[5], z, bg[1])));
            const float hgz = fmaf(Ag[6], x, fmaf(Ag[7], y, fmaf(Ag[8], z, bg[2])));
            const float iwp = frcp(hpz), iwg = frcp(hgz);
            const float du = fmaf(hpx, iwp, -hgx * iwg);
            const float dv = fmaf(hpy, iwp, -hgy * iwg);
            s_pj += fsqrt(fmaf(du, du, dv * dv));
        }
    }

    // ---- phase 2: ROI pixel loop (pv) ----
    const float* cx = coord + (size_t)n * 3 * HW;
    const int*   mk = mask + (size_t)n * HW;
    const float4* cx4 = (const float4*)cx;
    const float4* cy4 = (const float4*)(cx + HW);
    const float4* cz4 = (const float4*)(cx + 2 * HW);
    const int4*   mk4 = (const int4*)mk;

    float s_pv = 0.0f, s_m = 0.0f;
#pragma unroll
    for (int it = 0; it < HW / 4 / BLOCK; ++it) {
        const int p = it * BLOCK + tid;
        const float4 vx = cx4[p];
        const float4 vy = cy4[p];
        const float4 vz = cz4[p];
        const int4   mm = mk4[p];

        const float xs[4] = {vx.x, vx.y, vx.z, vx.w};
        const float ys[4] = {vy.x, vy.y, vy.z, vy.w};
        const float zs[4] = {vz.x, vz.y, vz.z, vz.w};
        const int   ms[4] = {mm.x, mm.y, mm.z, mm.w};

#pragma unroll
        for (int j = 0; j < 4; ++j) {
            const float x = xs[j], y = ys[j], z = zs[j];
            const float hpx = fmaf(Ap[0], x, fmaf(Ap[1], y, fmaf(Ap[2], z, bp[0])));
            const float hpy = fmaf(Ap[3], x, fmaf(Ap[4], y, fmaf(Ap[5], z, bp[1])));
            const float hpz = fmaf(Ap[6], x, fmaf(Ap[7], y, fmaf(Ap[8], z, bp[2])));
            const float hgx = fmaf(Ag[0], x, fmaf(Ag[1], y, fmaf(Ag[2], z, bg[0])));
            const float hgy = fmaf(Ag[3], x, fmaf(Ag[4], y, fmaf(Ag[5], z, bg[1])));
            const float hgz = fmaf(Ag[6], x, fmaf(Ag[7], y, fmaf(Ag[8], z, bg[2])));
            const float iwp = frcp(hpz), iwg = frcp(hgz);
            const float du = fmaf(hpx, iwp, -hgx * iwg);
            const float dv = fmaf(hpy, iwp, -hgy * iwg);
            const float d  = fsqrt(fmaf(du, du, dv * dv));
            const float fm = (ms[j] != 0) ? 1.0f : 0.0f;
            s_pv += d * fm;
            s_m  += fm;
        }
    }

    // ---- block reduction: 4 sums, wave64 shuffle then LDS ----
    float vals[4] = {s_ad, s_pj, s_pv, s_m};
#pragma unroll
    for (int k = 0; k < 4; ++k) {
#pragma unroll
        for (int off = 32; off > 0; off >>= 1)
            vals[k] += __shfl_down(vals[k], off, 64);
    }

    __shared__ float red[4][NWAVE];
    const int wave = tid >> 6;
    const int lane = tid & 63;
    if (lane == 0) {
#pragma unroll
        for (int k = 0; k < 4; ++k) red[k][wave] = vals[k];
    }
    __syncthreads();

    if (tid == 0) {
        float tot[4];
#pragma unroll
        for (int k = 0; k < 4; ++k) {
            float s = 0.0f;
#pragma unroll
            for (int w = 0; w < NWAVE; ++w) s += red[k][w];
            tot[k] = s;
        }

        float trace = 0.0f;
#pragma unroll
        for (int i = 0; i < 9; ++i) trace += Rp[i] * Rg[i];
        trace = fminf(fmaxf(trace, -1.0f), 3.0f);
        const float re = acosf((trace - 1.0f) * 0.5f) * (180.0f / 3.14159265358979323846f);
        const float te = sqrtf(dt[0] * dt[0] + dt[1] * dt[1] + dt[2] * dt[2]) * 100.0f;

        out[0 * NS + n] = re;
        out[1 * NS + n] = te;
        out[2 * NS + n] = tot[0] * (1.0f / MPTS) / dia;
        out[3 * NS + n] = tot[1] * (1.0f / MPTS);
        out[4 * NS + n] = tot[2] / fmaxf(tot[3], 1.0f);
    }
}

extern "C" void kernel_launch(void* const* d_in, const int* in_sizes, int n_in,
                              void* d_out, int out_size, void* d_ws, size_t ws_size,
                              hipStream_t stream) {
    const int*   obj_id = (const int*)  d_in[0];
    const float* cam_K  = (const float*)d_in[1];
    const float* gt_R   = (const float*)d_in[2];
    const float* gt_t   = (const float*)d_in[3];
    const float* pr_R   = (const float*)d_in[4];
    const float* pr_t   = (const float*)d_in[5];
    const float* coord  = (const float*)d_in[6];
    const int*   mask   = (const int*)  d_in[7];
    const float* mesh   = (const float*)d_in[8];
    const float* diam   = (const float*)d_in[9];
    float* out = (float*)d_out;

    score_kernel<<<NS, BLOCK, 0, stream>>>(obj_id, cam_K, gt_R, gt_t, pr_R, pr_t,
                                           coord, mask, mesh, diam, out);
}